// Round 2
// 453.334 us; speedup vs baseline: 1.0001x; 1.0001x over previous
//
#include <hip/hip_runtime.h>
#include <math.h>

#define ALPHA 0.5f
#define BETA 0.9f
#define Bsz 512
#define Tsz 512
#define Dsz 256
#define TILE 32
#define NTILE (Tsz / TILE)

__device__ __forceinline__ float wave_reduce_sum(float v) {
    v += __shfl_xor(v, 32, 64);
    v += __shfl_xor(v, 16, 64);
    v += __shfl_xor(v, 8, 64);
    v += __shfl_xor(v, 4, 64);
    v += __shfl_xor(v, 2, 64);
    v += __shfl_xor(v, 1, 64);
    return v;
}

__device__ __forceinline__ float wave_reduce_max(float v) {
    v = fmaxf(v, __shfl_xor(v, 32, 64));
    v = fmaxf(v, __shfl_xor(v, 16, 64));
    v = fmaxf(v, __shfl_xor(v, 8, 64));
    v = fmaxf(v, __shfl_xor(v, 4, 64));
    v = fmaxf(v, __shfl_xor(v, 2, 64));
    v = fmaxf(v, __shfl_xor(v, 1, 64));
    return v;
}

// async global->LDS, 16B/lane; LDS dest wave-uniform base + lane*16 (linear), linear source.
__device__ __forceinline__ void load_lds16(const float* g, float* l) {
    __builtin_amdgcn_global_load_lds(
        (const __attribute__((address_space(1))) void*)(g),
        (__attribute__((address_space(3))) void*)(l),
        16, 0, 0);
}

// Kernel A: per batch row b — mean-pooled q, t_max; then Qk = (q @ W_Q.T) @ W_K, scaled 1/sqrt(D)
// (unchanged — clean coalesced stream near its HBM share)
__global__ __launch_bounds__(256) void kA(const float* __restrict__ x,
                                          const float* __restrict__ ts,
                                          const unsigned char* __restrict__ pad,
                                          const float* __restrict__ WQ,
                                          const float* __restrict__ WK,
                                          float* __restrict__ qk,
                                          float* __restrict__ tmax_out) {
    const int b = blockIdx.x;
    const int tid = threadIdx.x;
    const int w = tid >> 6, lane = tid & 63;

    __shared__ float validS[Tsz];
    __shared__ float qpart[4][Dsz];
    __shared__ float qS[Dsz];
    __shared__ float QS[Dsz];
    __shared__ float red[8];
    __shared__ float tmaxS, cntS;

    float lmax = -1e30f;
    float lcnt = 0.f;
    for (int t = tid; t < Tsz; t += 256) {
        bool v = (pad[(size_t)b * Tsz + t] == 0);
        float tv = ts[(size_t)b * Tsz + t];
        validS[t] = v ? 1.f : 0.f;
        if (v) { lmax = fmaxf(lmax, tv); lcnt += 1.f; }
    }
    lmax = wave_reduce_max(lmax);
    lcnt = wave_reduce_sum(lcnt);
    if (lane == 0) { red[w] = lmax; red[4 + w] = lcnt; }
    __syncthreads();
    if (tid == 0) {
        tmaxS = fmaxf(fmaxf(red[0], red[1]), fmaxf(red[2], red[3]));
        cntS = fmaxf(red[4] + red[5] + red[6] + red[7], 1.f);
    }
    __syncthreads();

    const float* xb = x + (size_t)b * Tsz * Dsz;
    float4 a0 = make_float4(0.f, 0.f, 0.f, 0.f);
    float4 a1 = a0, a2 = a0, a3 = a0;
    const int tbase = w * 128;
    for (int i = 0; i < 128; i += 4) {
        const int t = tbase + i;
        float4 x0 = *(const float4*)(xb + (size_t)(t + 0) * Dsz + lane * 4);
        float4 x1 = *(const float4*)(xb + (size_t)(t + 1) * Dsz + lane * 4);
        float4 x2 = *(const float4*)(xb + (size_t)(t + 2) * Dsz + lane * 4);
        float4 x3 = *(const float4*)(xb + (size_t)(t + 3) * Dsz + lane * 4);
        const float v0 = validS[t], v1 = validS[t + 1], v2 = validS[t + 2], v3 = validS[t + 3];
        a0.x += v0 * x0.x; a0.y += v0 * x0.y; a0.z += v0 * x0.z; a0.w += v0 * x0.w;
        a1.x += v1 * x1.x; a1.y += v1 * x1.y; a1.z += v1 * x1.z; a1.w += v1 * x1.w;
        a2.x += v2 * x2.x; a2.y += v2 * x2.y; a2.z += v2 * x2.z; a2.w += v2 * x2.w;
        a3.x += v3 * x3.x; a3.y += v3 * x3.y; a3.z += v3 * x3.z; a3.w += v3 * x3.w;
    }
    float4 accq;
    accq.x = (a0.x + a1.x) + (a2.x + a3.x);
    accq.y = (a0.y + a1.y) + (a2.y + a3.y);
    accq.z = (a0.z + a1.z) + (a2.z + a3.z);
    accq.w = (a0.w + a1.w) + (a2.w + a3.w);
    qpart[w][lane * 4 + 0] = accq.x;
    qpart[w][lane * 4 + 1] = accq.y;
    qpart[w][lane * 4 + 2] = accq.z;
    qpart[w][lane * 4 + 3] = accq.w;
    __syncthreads();
    qS[tid] = (qpart[0][tid] + qpart[1][tid] + qpart[2][tid] + qpart[3][tid]) / cntS;
    __syncthreads();

    float Qi = 0.f;
    const float* wqrow = WQ + (size_t)tid * Dsz;
    #pragma unroll 4
    for (int d4 = 0; d4 < Dsz; d4 += 4) {
        float4 wv = *(const float4*)(wqrow + d4);
        Qi += wv.x * qS[d4] + wv.y * qS[d4 + 1] + wv.z * qS[d4 + 2] + wv.w * qS[d4 + 3];
    }
    QS[tid] = Qi;
    __syncthreads();

    float v = 0.f;
    #pragma unroll 8
    for (int e = 0; e < Dsz; ++e) {
        v += QS[e] * WK[(size_t)e * Dsz + tid];
    }
    qk[(size_t)b * Dsz + tid] = v * 0.0625f;
    if (tid == 0) tmax_out[b] = tmaxS;
}

// Kernel B: LDS-tiled double buffer via global_load_lds (LINEAR layout, no swizzle needed:
// score lanes use stride-8 chunk sets so every LDS read is contiguous per 8-lane group).
// 8-lane score groups -> 3-step shuffle reduce. Each wave stages/scores/accumulates only
// its own 8 rows per tile; one __syncthreads per tile is the only synchronization
// (its implicit vmcnt/lgkm drain gives the 2-phase prefetch schedule). Tiles descending-t,
// blocks reversed-b, to hit the L3-resident tail of kA's stream.
__global__ __launch_bounds__(256) void kB(const float* __restrict__ x,
                                          const float* __restrict__ ts,
                                          const unsigned char* __restrict__ pad,
                                          const float* __restrict__ qk,
                                          const float* __restrict__ tmax_in,
                                          const float* __restrict__ WV,
                                          const float* __restrict__ prevL,
                                          const float* __restrict__ prevM,
                                          const float* __restrict__ clsw,
                                          const float* __restrict__ clsb,
                                          float* __restrict__ out) {
    const int b = (Bsz - 1) - blockIdx.x;   // reverse: most-recently-cached batches first
    const int tid = threadIdx.x;
    const int w = tid >> 6, lane = tid & 63;
    const int rloc = lane >> 3;             // 0..7: row within this wave's 8-row group
    const int sub = lane & 7;               // 0..7: 8 threads per row

    __shared__ __align__(16) float buf[2][TILE][Dsz];   // 64 KB double-buffered tile
    __shared__ float lamS[Tsz];
    __shared__ float okS[Tsz];
    __shared__ float gS[TILE];              // per-wave disjoint: wave w uses [8w,8w+8)
    __shared__ float accS[4][Dsz];
    __shared__ float EGS[8];
    __shared__ float xwS[Dsz];
    __shared__ float red[4];
    __shared__ float red2[4];

    // ---- decay weights + validity per t ----
    const float tmax = tmax_in[b];
    for (int t = tid; t < Tsz; t += 256) {
        bool valid = (pad[(size_t)b * Tsz + t] == 0);
        float dt = fmaxf(tmax - ts[(size_t)b * Tsz + t], 0.f) * (1.f / 86400.f);
        lamS[t] = valid ? __expf(-ALPHA * dt) : 0.f;
        okS[t] = valid ? 1.f : 0.f;
    }

    // ---- preload qk fragment: lane (rloc,sub) owns chunks {8*jj+sub}, jj=0..7 ----
    float4 qkr[8];
    #pragma unroll
    for (int jj = 0; jj < 8; ++jj)
        qkr[jj] = *(const float4*)(qk + (size_t)b * Dsz + ((jj * 8 + sub) << 2));

    const float* xb = x + (size_t)b * Tsz * Dsz;

    // ---- prologue: stage highest-t tile into buf[0] (wave w stages its own rows) ----
    {
        const int t0 = (NTILE - 1) * TILE;
        #pragma unroll
        for (int k = 0; k < 8; ++k) {
            const int r = w * 8 + k;
            load_lds16(xb + (size_t)(t0 + r) * Dsz + lane * 4, &buf[0][r][0]);
        }
    }
    __syncthreads();   // drains vmcnt (tile landed) + makes lamS/okS visible

    float4 acc = make_float4(0.f, 0.f, 0.f, 0.f);
    float E = 0.f, G = 0.f;   // each row counted 8x (identical across subs); /8 at the end
    int cur = 0;

    for (int it = 0; it < NTILE; ++it) {
        const int tile = (NTILE - 1) - it;

        // ---- prefetch next (descending) tile into the other buffer ----
        if (it + 1 < NTILE) {
            const int t0 = (tile - 1) * TILE;
            #pragma unroll
            for (int k = 0; k < 8; ++k) {
                const int r = w * 8 + k;
                load_lds16(xb + (size_t)(t0 + r) * Dsz + lane * 4, &buf[cur ^ 1][r][0]);
            }
        }

        // ---- score: row r = w*8+rloc; lane reads chunks {8*jj+sub} (contiguous/group) ----
        const int r = w * 8 + rloc;
        const float* rowp = &buf[cur][r][0];
        float s = 0.f;
        #pragma unroll
        for (int jj = 0; jj < 8; ++jj) {
            const float4 xv = *(const float4*)(rowp + ((jj * 8 + sub) << 2));
            s += xv.x * qkr[jj].x + xv.y * qkr[jj].y + xv.z * qkr[jj].z + xv.w * qkr[jj].w;
        }
        // reduce across the 8 subs (3 steps; all 8 lanes end with identical s)
        s += __shfl_xor(s, 1, 64);
        s += __shfl_xor(s, 2, 64);
        s += __shfl_xor(s, 4, 64);
        const int tglob = tile * TILE + r;
        const float e = okS[tglob] * __expf(s);
        const float g = lamS[tglob] * e;
        E += e; G += g;
        if (sub == 0) gS[r] = g;   // intra-wave producer->consumer only

        // ---- accum: this wave's 8 rows, per-lane d-chunk (canonical contiguous read) ----
        #pragma unroll
        for (int k = 0; k < 8; ++k) {
            const float g_k = gS[w * 8 + k];
            const float4 xv = *(const float4*)(&buf[cur][w * 8 + k][lane * 4]);
            acc.x += g_k * xv.x; acc.y += g_k * xv.y; acc.z += g_k * xv.z; acc.w += g_k * xv.w;
        }

        __syncthreads();   // drains vmcnt (prefetch landed) + lgkm (reads done) for swap
        cur ^= 1;
    }

    accS[w][lane * 4 + 0] = acc.x;
    accS[w][lane * 4 + 1] = acc.y;
    accS[w][lane * 4 + 2] = acc.z;
    accS[w][lane * 4 + 3] = acc.w;
    float Ew = wave_reduce_sum(E) * 0.125f;   // undo 8x sub redundancy (exact, pow2)
    float Gw = wave_reduce_sum(G) * 0.125f;
    if (lane == 0) { EGS[w] = Ew; EGS[4 + w] = Gw; }
    __syncthreads();

    {
        float Et = EGS[0] + EGS[1] + EGS[2] + EGS[3];
        float Gt = EGS[4] + EGS[5] + EGS[6] + EGS[7];
        float denom = Gt + 1e-8f * Et;  // softmax denominators cancel
        float accd = accS[0][tid] + accS[1][tid] + accS[2][tid] + accS[3][tid];
        xwS[tid] = (denom > 0.f) ? accd / denom : 0.f;
    }
    __syncthreads();

    // ---- epilogue: L = W_V @ xw; delta; M; p; writes ----
    float Le = 0.f;
    const float* wvrow = WV + (size_t)tid * Dsz;
    #pragma unroll 4
    for (int d4 = 0; d4 < Dsz; d4 += 4) {
        float4 wv = *(const float4*)(wvrow + d4);
        Le += wv.x * xwS[d4] + wv.y * xwS[d4 + 1] + wv.z * xwS[d4 + 2] + wv.w * xwS[d4 + 3];
    }
    float delta = Le - prevL[(size_t)b * Dsz + tid];

    float ssq = wave_reduce_sum(delta * delta);
    if (lane == 0) red[w] = ssq;
    __syncthreads();
    float nrm = sqrtf(red[0] + red[1] + red[2] + red[3]);
    float M = BETA * prevM[b] + (1.f - BETA) * nrm;

    float pp = Le * clsw[tid] + delta * clsw[Dsz + tid];
    float psum = wave_reduce_sum(pp);
    if (lane == 0) red2[w] = psum;
    __syncthreads();

    float* out_p = out;
    float* out_T = out + Bsz;
    float* out_L = out + Bsz + (size_t)Bsz * (2 * Dsz + 1);
    float* out_M = out + Bsz + (size_t)Bsz * (2 * Dsz + 1) + (size_t)Bsz * Dsz;

    out_T[(size_t)b * (2 * Dsz + 1) + tid] = Le;
    out_T[(size_t)b * (2 * Dsz + 1) + Dsz + tid] = delta;
    out_L[(size_t)b * Dsz + tid] = Le;
    if (tid == 0) {
        float p = red2[0] + red2[1] + red2[2] + red2[3] + M * clsw[2 * Dsz] + clsb[0];
        out_p[b] = p;
        out_T[(size_t)b * (2 * Dsz + 1) + 2 * Dsz] = M;
        out_M[b] = M;
    }
}

extern "C" void kernel_launch(void* const* d_in, const int* in_sizes, int n_in,
                              void* d_out, int out_size, void* d_ws, size_t ws_size,
                              hipStream_t stream) {
    const float* x     = (const float*)d_in[0];
    const float* ts    = (const float*)d_in[1];
    const float* prevL = (const float*)d_in[2];
    const float* prevM = (const float*)d_in[3];
    const unsigned char* pad = (const unsigned char*)d_in[4];
    const float* WQ    = (const float*)d_in[5];
    const float* WK    = (const float*)d_in[6];
    const float* WV    = (const float*)d_in[7];
    const float* clsw  = (const float*)d_in[8];
    const float* clsb  = (const float*)d_in[9];

    float* ws   = (float*)d_ws;
    float* qk   = ws;                 // [B, D]
    float* tmax = ws + Bsz * Dsz;     // [B]

    kA<<<Bsz, 256, 0, stream>>>(x, ts, pad, WQ, WK, qk, tmax);
    kB<<<Bsz, 256, 0, stream>>>(x, ts, pad, qk, tmax, WV, prevL, prevM, clsw, clsb, (float*)d_out);
}

// Round 3
// 442.173 us; speedup vs baseline: 1.0254x; 1.0252x over previous
//
#include <hip/hip_runtime.h>
#include <math.h>

#define ALPHA 0.5f
#define BETA 0.9f
#define Bsz 512
#define Tsz 512
#define Dsz 256
#define TILE 32
#define NTILE (Tsz / TILE)

__device__ __forceinline__ float wave_reduce_sum(float v) {
    v += __shfl_xor(v, 32, 64);
    v += __shfl_xor(v, 16, 64);
    v += __shfl_xor(v, 8, 64);
    v += __shfl_xor(v, 4, 64);
    v += __shfl_xor(v, 2, 64);
    v += __shfl_xor(v, 1, 64);
    return v;
}

__device__ __forceinline__ float wave_reduce_max(float v) {
    v = fmaxf(v, __shfl_xor(v, 32, 64));
    v = fmaxf(v, __shfl_xor(v, 16, 64));
    v = fmaxf(v, __shfl_xor(v, 8, 64));
    v = fmaxf(v, __shfl_xor(v, 4, 64));
    v = fmaxf(v, __shfl_xor(v, 2, 64));
    v = fmaxf(v, __shfl_xor(v, 1, 64));
    return v;
}

// async global->LDS, 16B/lane; LDS dest wave-uniform base + lane*16 (linear), linear source.
__device__ __forceinline__ void load_lds16(const float* g, float* l) {
    __builtin_amdgcn_global_load_lds(
        (const __attribute__((address_space(1))) void*)(g),
        (__attribute__((address_space(3))) void*)(l),
        16, 0, 0);
}

// Fused kernel: one block per batch row b.
//   phase 0: ts/pad -> valid flags, tmax, count, lam (in LDS, in-place transform)
//   phase 1: ascending-t stream over x[b] -> mean-pooled q          (HBM-bound)
//   phase 2: Q = q@WQ.T ; qk = (Q@WK)/16                            (in-LDS, tiny)
//   phase 3: descending-t LDS-tiled pass -> scores, E/G, acc        (L3-hot re-read)
//   phase 4: L = WV@xw, delta, M, T_event, p
// No workspace, no qk/tmax global round-trip, one launch.
__global__ __launch_bounds__(256) void fused(const float* __restrict__ x,
                                             const float* __restrict__ ts,
                                             const unsigned char* __restrict__ pad,
                                             const float* __restrict__ WQ,
                                             const float* __restrict__ WK,
                                             const float* __restrict__ WV,
                                             const float* __restrict__ prevL,
                                             const float* __restrict__ prevM,
                                             const float* __restrict__ clsw,
                                             const float* __restrict__ clsb,
                                             float* __restrict__ out) {
    const int b = blockIdx.x;
    const int tid = threadIdx.x;
    const int w = tid >> 6, lane = tid & 63;
    const int rloc = lane >> 3;             // 0..7: row within this wave's 8-row group
    const int sub = lane & 7;               // 0..7: 8 threads per row

    __shared__ __align__(16) float buf[2][TILE][Dsz];   // 64 KB double-buffered x tile
    __shared__ float lamS[Tsz];             // phase 0: raw ts; then lam
    __shared__ float okS[Tsz];
    __shared__ float part[4][Dsz];          // phase 1: q partials; phase 3: acc partials
    __shared__ float qS[Dsz];
    __shared__ float QS[Dsz];
    __shared__ __align__(16) float qkS[Dsz];
    __shared__ float gS[TILE];              // per-wave disjoint: wave w uses [8w,8w+8)
    __shared__ float xwS[Dsz];
    __shared__ float EGS[8];
    __shared__ float red[8];
    __shared__ float red2[4];
    __shared__ float tmaxS, cntS;

    // ---- phase 0a: valid flags, stash raw ts, masked t_max, valid count ----
    float lmax = -1e30f;
    float lcnt = 0.f;
    for (int t = tid; t < Tsz; t += 256) {
        bool v = (pad[(size_t)b * Tsz + t] == 0);
        float tv = ts[(size_t)b * Tsz + t];
        okS[t] = v ? 1.f : 0.f;
        lamS[t] = tv;
        if (v) { lmax = fmaxf(lmax, tv); lcnt += 1.f; }
    }
    lmax = wave_reduce_max(lmax);
    lcnt = wave_reduce_sum(lcnt);
    if (lane == 0) { red[w] = lmax; red[4 + w] = lcnt; }
    __syncthreads();
    if (tid == 0) {
        tmaxS = fmaxf(fmaxf(red[0], red[1]), fmaxf(red[2], red[3]));
        cntS = fmaxf(red[4] + red[5] + red[6] + red[7], 1.f);
    }
    __syncthreads();

    // ---- phase 0b: lam transform in place (each thread re-touches its own t's) ----
    const float tmax = tmaxS;
    for (int t = tid; t < Tsz; t += 256) {
        float dt = fmaxf(tmax - lamS[t], 0.f) * (1.f / 86400.f);
        lamS[t] = okS[t] * __expf(-ALPHA * dt);
    }

    // ---- phase 1: q = sum_t valid_t * x[b,t,:] / count (ascending t) ----
    const float* xb = x + (size_t)b * Tsz * Dsz;
    float4 a0 = make_float4(0.f, 0.f, 0.f, 0.f);
    float4 a1 = a0, a2 = a0, a3 = a0;
    const int tbase = w * 128;
    for (int i = 0; i < 128; i += 4) {
        const int t = tbase + i;
        float4 x0 = *(const float4*)(xb + (size_t)(t + 0) * Dsz + lane * 4);
        float4 x1 = *(const float4*)(xb + (size_t)(t + 1) * Dsz + lane * 4);
        float4 x2 = *(const float4*)(xb + (size_t)(t + 2) * Dsz + lane * 4);
        float4 x3 = *(const float4*)(xb + (size_t)(t + 3) * Dsz + lane * 4);
        const float v0 = okS[t], v1 = okS[t + 1], v2 = okS[t + 2], v3 = okS[t + 3];
        a0.x += v0 * x0.x; a0.y += v0 * x0.y; a0.z += v0 * x0.z; a0.w += v0 * x0.w;
        a1.x += v1 * x1.x; a1.y += v1 * x1.y; a1.z += v1 * x1.z; a1.w += v1 * x1.w;
        a2.x += v2 * x2.x; a2.y += v2 * x2.y; a2.z += v2 * x2.z; a2.w += v2 * x2.w;
        a3.x += v3 * x3.x; a3.y += v3 * x3.y; a3.z += v3 * x3.z; a3.w += v3 * x3.w;
    }
    float4 accq;
    accq.x = (a0.x + a1.x) + (a2.x + a3.x);
    accq.y = (a0.y + a1.y) + (a2.y + a3.y);
    accq.z = (a0.z + a1.z) + (a2.z + a3.z);
    accq.w = (a0.w + a1.w) + (a2.w + a3.w);
    part[w][lane * 4 + 0] = accq.x;
    part[w][lane * 4 + 1] = accq.y;
    part[w][lane * 4 + 2] = accq.z;
    part[w][lane * 4 + 3] = accq.w;

    // ---- stage highest-t tile for phase 3 now (these rows are L1/L2-hot from pass 1) ----
    {
        const int t0 = (NTILE - 1) * TILE;
        #pragma unroll
        for (int k = 0; k < 8; ++k) {
            const int r = w * 8 + k;
            load_lds16(xb + (size_t)(t0 + r) * Dsz + lane * 4, &buf[0][r][0]);
        }
    }
    __syncthreads();   // drains vmcnt: tile landed; part[] visible

    qS[tid] = (part[0][tid] + part[1][tid] + part[2][tid] + part[3][tid]) / cntS;
    __syncthreads();

    // ---- phase 2: Q[i] = sum_d q[d] * WQ[i,d] ----
    float Qi = 0.f;
    const float* wqrow = WQ + (size_t)tid * Dsz;
    #pragma unroll 4
    for (int d4 = 0; d4 < Dsz; d4 += 4) {
        float4 wv = *(const float4*)(wqrow + d4);
        Qi += wv.x * qS[d4] + wv.y * qS[d4 + 1] + wv.z * qS[d4 + 2] + wv.w * qS[d4 + 3];
    }
    QS[tid] = Qi;
    __syncthreads();

    // ---- phase 2b: qk[d] = (sum_e Q[e] * WK[e,d]) / 16 ----
    {
        float v0 = 0.f, v1 = 0.f, v2 = 0.f, v3 = 0.f;
        #pragma unroll 4
        for (int e = 0; e < Dsz; e += 4) {
            v0 += QS[e + 0] * WK[(size_t)(e + 0) * Dsz + tid];
            v1 += QS[e + 1] * WK[(size_t)(e + 1) * Dsz + tid];
            v2 += QS[e + 2] * WK[(size_t)(e + 2) * Dsz + tid];
            v3 += QS[e + 3] * WK[(size_t)(e + 3) * Dsz + tid];
        }
        qkS[tid] = ((v0 + v1) + (v2 + v3)) * 0.0625f;
    }
    __syncthreads();

    // ---- phase 3: descending-t tiled pass; lane (rloc,sub) owns chunks {8*jj+sub} ----
    float4 qkr[8];
    #pragma unroll
    for (int jj = 0; jj < 8; ++jj)
        qkr[jj] = *(const float4*)(&qkS[(jj * 8 + sub) << 2]);

    float4 acc = make_float4(0.f, 0.f, 0.f, 0.f);
    float E = 0.f, G = 0.f;   // each row counted 8x (identical across subs); /8 at the end
    int cur = 0;

    for (int it = 0; it < NTILE; ++it) {
        const int tile = (NTILE - 1) - it;

        // prefetch next (descending) tile into the other buffer
        if (it + 1 < NTILE) {
            const int t0 = (tile - 1) * TILE;
            #pragma unroll
            for (int k = 0; k < 8; ++k) {
                const int r = w * 8 + k;
                load_lds16(xb + (size_t)(t0 + r) * Dsz + lane * 4, &buf[cur ^ 1][r][0]);
            }
        }

        // score: row r = w*8+rloc; 8-lane groups read contiguous 128B (conflict-free)
        const int r = w * 8 + rloc;
        const float* rowp = &buf[cur][r][0];
        float s = 0.f;
        #pragma unroll
        for (int jj = 0; jj < 8; ++jj) {
            const float4 xv = *(const float4*)(rowp + ((jj * 8 + sub) << 2));
            s += xv.x * qkr[jj].x + xv.y * qkr[jj].y + xv.z * qkr[jj].z + xv.w * qkr[jj].w;
        }
        s += __shfl_xor(s, 1, 64);
        s += __shfl_xor(s, 2, 64);
        s += __shfl_xor(s, 4, 64);
        const int tglob = tile * TILE + r;
        const float e = okS[tglob] * __expf(s);
        const float g = lamS[tglob] * e;
        E += e; G += g;
        if (sub == 0) gS[r] = g;   // intra-wave producer->consumer only

        // accum: this wave's 8 rows, per-lane contiguous d-chunk (conflict-free)
        #pragma unroll
        for (int k = 0; k < 8; ++k) {
            const float g_k = gS[w * 8 + k];
            const float4 xv = *(const float4*)(&buf[cur][w * 8 + k][lane * 4]);
            acc.x += g_k * xv.x; acc.y += g_k * xv.y; acc.z += g_k * xv.z; acc.w += g_k * xv.w;
        }

        __syncthreads();   // drains vmcnt (prefetch landed) + lgkm (reads done) for swap
        cur ^= 1;
    }

    part[w][lane * 4 + 0] = acc.x;
    part[w][lane * 4 + 1] = acc.y;
    part[w][lane * 4 + 2] = acc.z;
    part[w][lane * 4 + 3] = acc.w;
    float Ew = wave_reduce_sum(E) * 0.125f;   // undo 8x sub redundancy (exact, pow2)
    float Gw = wave_reduce_sum(G) * 0.125f;
    if (lane == 0) { EGS[w] = Ew; EGS[4 + w] = Gw; }
    __syncthreads();

    {
        float Et = EGS[0] + EGS[1] + EGS[2] + EGS[3];
        float Gt = EGS[4] + EGS[5] + EGS[6] + EGS[7];
        float denom = Gt + 1e-8f * Et;  // softmax denominators cancel
        float accd = part[0][tid] + part[1][tid] + part[2][tid] + part[3][tid];
        xwS[tid] = (denom > 0.f) ? accd / denom : 0.f;
    }
    __syncthreads();

    // ---- phase 4: L = W_V @ xw; delta; M; p; writes ----
    float Le = 0.f;
    const float* wvrow = WV + (size_t)tid * Dsz;
    #pragma unroll 4
    for (int d4 = 0; d4 < Dsz; d4 += 4) {
        float4 wv = *(const float4*)(wvrow + d4);
        Le += wv.x * xwS[d4] + wv.y * xwS[d4 + 1] + wv.z * xwS[d4 + 2] + wv.w * xwS[d4 + 3];
    }
    float delta = Le - prevL[(size_t)b * Dsz + tid];

    float ssq = wave_reduce_sum(delta * delta);
    if (lane == 0) red[w] = ssq;
    __syncthreads();
    float nrm = sqrtf(red[0] + red[1] + red[2] + red[3]);
    float M = BETA * prevM[b] + (1.f - BETA) * nrm;

    float pp = Le * clsw[tid] + delta * clsw[Dsz + tid];
    float psum = wave_reduce_sum(pp);
    if (lane == 0) red2[w] = psum;
    __syncthreads();

    float* out_p = out;
    float* out_T = out + Bsz;
    float* out_L = out + Bsz + (size_t)Bsz * (2 * Dsz + 1);
    float* out_M = out + Bsz + (size_t)Bsz * (2 * Dsz + 1) + (size_t)Bsz * Dsz;

    out_T[(size_t)b * (2 * Dsz + 1) + tid] = Le;
    out_T[(size_t)b * (2 * Dsz + 1) + Dsz + tid] = delta;
    out_L[(size_t)b * Dsz + tid] = Le;
    if (tid == 0) {
        float p = red2[0] + red2[1] + red2[2] + red2[3] + M * clsw[2 * Dsz] + clsb[0];
        out_p[b] = p;
        out_T[(size_t)b * (2 * Dsz + 1) + 2 * Dsz] = M;
        out_M[b] = M;
    }
}

extern "C" void kernel_launch(void* const* d_in, const int* in_sizes, int n_in,
                              void* d_out, int out_size, void* d_ws, size_t ws_size,
                              hipStream_t stream) {
    const float* x     = (const float*)d_in[0];
    const float* ts    = (const float*)d_in[1];
    const float* prevL = (const float*)d_in[2];
    const float* prevM = (const float*)d_in[3];
    const unsigned char* pad = (const unsigned char*)d_in[4];
    const float* WQ    = (const float*)d_in[5];
    const float* WK    = (const float*)d_in[6];
    const float* WV    = (const float*)d_in[7];
    const float* clsw  = (const float*)d_in[8];
    const float* clsb  = (const float*)d_in[9];

    (void)d_ws; (void)ws_size;  // fully fused: no workspace needed

    fused<<<Bsz, 256, 0, stream>>>(x, ts, pad, WQ, WK, WV, prevL, prevM, clsw, clsb,
                                   (float*)d_out);
}